// Round 17
// baseline (5254.820 us; speedup 1.0000x reference)
//
#include <hip/hip_runtime.h>
#include <hip/hip_bf16.h>
#include <math.h>

// ---------------- types ----------------
typedef __attribute__((ext_vector_type(4))) float f32x4;
typedef __attribute__((ext_vector_type(8))) short short8;

#define NTOK 25088   // B*H*W = 8*56*56
#define DD   640

__device__ __forceinline__ void gload_lds16(const void* g, void* l) {
    __builtin_amdgcn_global_load_lds((const __attribute__((address_space(1))) void*)g,
                                     (__attribute__((address_space(3))) void*)l,
                                     16, 0, 0);
}

// exact rewrite of tanh-gelu: 0.5t(1+tanh(v)) = t * sigmoid(2v)
__device__ __forceinline__ float gelu_f(float t) {
    float u = 1.5957691216057308f * (t + 0.044715f * t * t * t);
    float e = __builtin_amdgcn_exp2f(u * -1.4426950408889634f);   // exp(-u)
    return t / (1.f + e);
}

__device__ __forceinline__ float bf2f(short u) {
    union { unsigned int i; float f; } cv;
    cv.i = ((unsigned int)(unsigned short)u) << 16;
    return cv.f;
}
__device__ __forceinline__ short f2bf(float f) {
    return (short)__bfloat16_as_short(__float2bfloat16(f));
}

// ---------------- constants init: NSCT filters + padded biases ----------------
__global__ void init_consts(float* __restrict__ filt, float* __restrict__ linbp,
                            const float* __restrict__ lin_b, float* __restrict__ convbp,
                            const float* __restrict__ conv_b) {
    int t = threadIdx.x;
    if (t == 0) {
        float g[25]; float s = 0.f;
        for (int i = 0; i < 5; i++) for (int j = 0; j < 5; j++) {
            float yy = (float)(i - 2), xx = (float)(j - 2);
            float v = expf(-(xx*xx + yy*yy) * 0.25f);
            g[i*5+j] = v; s += v;
        }
        for (int i = 0; i < 25; i++) { g[i] /= s; filt[i] = g[i]; }
        for (int k = 0; k < 8; k++) {
            float th = (float)k * 3.14159265358979323846f / 8.f;
            float ct = cosf(th), st = sinf(th);
            float d[25]; float mean = 0.f;
            for (int i = 0; i < 5; i++) for (int j = 0; j < 5; j++) {
                float yy = (float)(i - 2), xx = (float)(j - 2);
                d[i*5+j] = (ct*xx + st*yy) * g[i*5+j];
                mean += d[i*5+j];
            }
            mean *= (1.f/25.f);
            float ss = 0.f;
            for (int i = 0; i < 25; i++) { d[i] -= mean; ss += d[i]*d[i]; }
            ss = sqrtf(ss);
            for (int i = 0; i < 25; i++) filt[(k+1)*25 + i] = d[i] / ss;
        }
    }
    for (int i = t; i < 640; i += 256) linbp[i]  = (i < 576) ? lin_b[i]  : 0.f;
    for (int i = t; i < 128; i += 256) convbp[i] = (i < 64)  ? conv_b[i] : 0.f;
}

// ---------------- weight transpose+cast: dst[n][k] = bf16(src[k][n]), zero-pad n>=Nsrc ----------------
__global__ __launch_bounds__(256)
void wtrans_kernel(const float* __restrict__ src, __hip_bfloat16* __restrict__ dst,
                   int K, int Nsrc) {
    __shared__ float tile[32][33];
    const int n0 = blockIdx.x * 32;
    const int k0 = blockIdx.y * 32;
    const int tx = threadIdx.x, ty = threadIdx.y;
    #pragma unroll
    for (int r = ty; r < 32; r += 8) {
        int k = k0 + r, n = n0 + tx;
        tile[r][tx] = (n < Nsrc) ? src[(long)k * Nsrc + n] : 0.f;
    }
    __syncthreads();
    #pragma unroll
    for (int r = ty; r < 32; r += 8) {
        int n = n0 + r, k = k0 + tx;
        dst[(long)n * K + k] = __float2bfloat16(tile[tx][r]);
    }
}

__global__ void wcast_kernel(const float* __restrict__ src, __hip_bfloat16* __restrict__ dst,
                             int count, int total) {
    int i = blockIdx.x * 256 + threadIdx.x;
    if (i < total) dst[i] = __float2bfloat16(i < count ? src[i] : 0.f);
}

// ---- prep: relu + 9-band NSCT conv + concat -> x3 bf16 AND fused LN1(layer0) -> bufA bf16 ----
__global__ __launch_bounds__(256)
void prep_kernel(const float* __restrict__ x, const float* __restrict__ filt,
                 __hip_bfloat16* __restrict__ x3, const float* __restrict__ g1,
                 const float* __restrict__ b1, __hip_bfloat16* __restrict__ lnout) {
    __shared__ float sf[225];
    for (int i = threadIdx.x; i < 225; i += 256) sf[i] = filt[i];
    __syncthreads();
    int id = blockIdx.x * 256 + threadIdx.x;   // B*H*W*C
    int c = id & 63;
    int pix = id >> 6;
    int w = pix % 56, h = (pix / 56) % 56, b = pix / 3136;
    const float* xp = x + (long)(b * 64 + c) * 3136;
    float nb[25];
    #pragma unroll
    for (int dy = 0; dy < 5; dy++) {
        int hy = h + dy - 2;
        #pragma unroll
        for (int dx = 0; dx < 5; dx++) {
            int wx = w + dx - 2;
            float v = 0.f;
            if (hy >= 0 && hy < 56 && wx >= 0 && wx < 56) v = fmaxf(xp[hy*56 + wx], 0.f);
            nb[dy*5 + dx] = v;
        }
    }
    float bo[9];
    __hip_bfloat16* orow = x3 + (long)pix * DD;
    float s = 0.f, s2 = 0.f;
    #pragma unroll
    for (int band = 0; band < 9; band++) {
        float a = 0.f;
        #pragma unroll
        for (int t = 0; t < 25; t++) a += nb[t] * sf[band*25 + t];
        bo[band] = a;
        orow[band*64 + c] = __float2bfloat16(a);
        s += a; s2 += a * a;
    }
    const float ctr = nb[12];
    orow[576 + c] = __float2bfloat16(ctr);     // relu(x) center copy
    s += ctr; s2 += ctr * ctr;
    #pragma unroll
    for (int o = 32; o > 0; o >>= 1) { s += __shfl_xor(s, o); s2 += __shfl_xor(s2, o); }
    const float mean = s * (1.f/640.f);
    const float var  = s2 * (1.f/640.f) - mean * mean;
    const float inv  = 1.f / sqrtf(var + 1e-5f);
    __hip_bfloat16* ob = lnout + (long)pix * DD;
    #pragma unroll
    for (int band = 0; band < 9; band++) {
        int ci = band*64 + c;
        ob[ci] = __float2bfloat16((bo[band] - mean) * inv * g1[ci] + b1[ci]);
    }
    ob[576 + c] = __float2bfloat16((ctr - mean) * inv * g1[576 + c] + b1[576 + c]);
}

// ---------------- LayerNorm (per-token over 640, bf16 in) -> bf16 ----------------
__global__ __launch_bounds__(256)
void ln_kernel(const __hip_bfloat16* __restrict__ xin, const float* __restrict__ g,
               const float* __restrict__ bt, __hip_bfloat16* __restrict__ out) {
    const int lane = threadIdx.x & 63;
    const long tok = (long)blockIdx.x * 4 + (threadIdx.x >> 6);
    const __hip_bfloat16* xr = xin + tok * DD;
    float v[10]; float s = 0.f, s2 = 0.f;
    #pragma unroll
    for (int i = 0; i < 10; i++) {
        float t = __bfloat162float(xr[lane + (i << 6)]);
        v[i] = t; s += t; s2 += t*t;
    }
    #pragma unroll
    for (int o = 32; o > 0; o >>= 1) { s += __shfl_xor(s, o); s2 += __shfl_xor(s2, o); }
    const float mean = s * (1.f/640.f);
    const float var  = s2 * (1.f/640.f) - mean * mean;
    const float inv  = 1.f / sqrtf(var + 1e-5f);
    __hip_bfloat16* orow = out + tok * DD;
    #pragma unroll
    for (int i = 0; i < 10; i++) {
        int c = lane + (i << 6);
        orow[c] = __float2bfloat16((v[i] - mean) * inv * g[c] + bt[c]);
    }
}

// ========== 8-phase 256x256x64 GEMM — symmetric schedule (R16-correct, spill fixed) ==========
// R16 counters: VGPR_Count 128 + WRITE_SIZE 1.46GB = acc spilled to scratch. Cause was
// __launch_bounds__(512,2) capping the unified reg budget at ~128/thread. This kernel needs
// ~220 (acc 128 + bq 32 + af 16 + addressing). LDS (128KB of 160KB) already caps residency
// at 1 block/CU (8 waves) — the m201 reference config — so (512,1) loses nothing.
// Schedule identical to R16 (passed correctness): tile tau buf d=tau&1, phases q0..3:
//   q0: all B-frags->regs + A quad0; stage A(d^1,h0,tau+1)   q1: A quad1; stage A(d^1,h1,tau+1)
//   q2: A quad2; stage B(d,h0,tau+2)   q3: A quad3; stage B(d,h1,tau+2); vmcnt(4)
__global__ __launch_bounds__(512, 1)
void gemm8p_kernel(const __hip_bfloat16* __restrict__ A,
                   const __hip_bfloat16* __restrict__ Bt,
                   const float* __restrict__ bias,
                   const __hip_bfloat16* __restrict__ resid,
                   __hip_bfloat16* __restrict__ Cb,
                   int K, int ldb, int col_off, int ncb,
                   int act_gelu, int nvalid) {
    extern __shared__ __align__(16) char sm[];   // A:[0,65536) B:[65536,131072)

    const int tid  = threadIdx.x;
    const int lane = tid & 63;
    const int wid  = tid >> 6;
    const int wr   = wid >> 2;         // 0..1  M half (128 rows)
    const int wc   = wid & 3;          // 0..3  N quarter (64 cols)

    // ---- bijective XCD-aware block remap (m204) ----
    const int gx   = gridDim.x;
    const int nwg  = gx * gridDim.y;
    const int orig = blockIdx.y * gx + blockIdx.x;
    const int qq = nwg >> 3, rr = nwg & 7;
    const int xcd = orig & 7, lid = orig >> 3;
    const int wg = (xcd < rr ? xcd * (qq + 1) : rr * (qq + 1) + (xcd - rr) * qq) + lid;
    const long m0 = (long)(wg / gx) * 256;
    const long n0 = (long)(wg % gx) * 256;

    const bool wact = ((int)n0 + (wc << 6)) < nvalid;

    f32x4 acc[8][4];
    #pragma unroll
    for (int i = 0; i < 8; i++)
        #pragma unroll
        for (int j = 0; j < 4; j++) acc[i][j] = (f32x4){0.f, 0.f, 0.f, 0.f};

    // staging: half-tile = 128 rows x 64k (16KB); thread covers rows rs, rs+64; slot sl
    const int rs  = tid >> 3;                  // 0..63
    const int sl  = tid & 7;
    const int ssl = sl ^ (rs & 7);             // inverse-swizzled source slot (rows+64k same)
    const __hip_bfloat16* Ag = A  + (m0 + rs) * (long)K + (ssl << 3);
    const __hip_bfloat16* Bg = Bt + (n0 + rs) * (long)K + (ssl << 3);
    char* lA = sm + rs * 128 + sl * 16;        // linear LDS dest
    char* lB = lA + 65536;

    const int frow = lane & 15;
    const int fks  = lane >> 4;                // 0..3
    const int fr7  = frow & 7;
    const int c0 = ((fks ^ fr7) << 4);         // ks=0 swizzled byte col
    const int c1 = (((4 | fks) ^ fr7) << 4);   // ks=1

#define STA(D, H, KT) do { const long ko = (long)(KT) << 6;                         \
    gload_lds16(Ag + (long)((H)*128) * K + ko,      lA + (D)*32768 + (H)*16384);    \
    gload_lds16(Ag + (long)((H)*128+64) * K + ko,   lA + (D)*32768 + (H)*16384 + 8192); } while(0)
#define STB(D, H, KT) do { const long ko = (long)(KT) << 6;                         \
    gload_lds16(Bg + (long)((H)*128) * K + ko,      lB + (D)*32768 + (H)*16384);    \
    gload_lds16(Bg + (long)((H)*128+64) * K + ko,   lB + (D)*32768 + (H)*16384 + 8192); } while(0)

    const int nt = K >> 6;                     // 10 or 40 (even)
    // prologue: tile0 (A+B) and B(1); drain fully
    STA(0, 0, 0); STA(0, 1, 0);
    STB(0, 0, 0); STB(0, 1, 0);
    STB(1, 0, 1); STB(1, 1, 1);
    asm volatile("s_waitcnt vmcnt(0)" ::: "memory");
    __builtin_amdgcn_s_barrier();

    short8 bq[4][2];

#define PHASE(D, Q, STAGE_STMT, TAIL_STMT)                                          \
    do {                                                                            \
        short8 af[2][2];                                                            \
        const char* pA = sm + (D)*32768;                                            \
        const char* pB = sm + 65536 + (D)*32768;                                    \
        if (wact) {                                                                 \
            if ((Q) == 0) {                                                         \
                _Pragma("unroll")                                                   \
                for (int nj = 0; nj < 4; ++nj) {                                    \
                    const int R = (wc << 6) + (nj << 4) + frow;                     \
                    bq[nj][0] = *(const short8*)(pB + R * 128 + c0);                \
                    bq[nj][1] = *(const short8*)(pB + R * 128 + c1);                \
                }                                                                   \
            }                                                                       \
            _Pragma("unroll")                                                       \
            for (int m2 = 0; m2 < 2; ++m2) {                                        \
                const int R = (wr << 7) + ((((Q) << 1) | m2) << 4) + frow;          \
                af[m2][0] = *(const short8*)(pA + R * 128 + c0);                    \
                af[m2][1] = *(const short8*)(pA + R * 128 + c1);                    \
            }                                                                       \
        }                                                                           \
        STAGE_STMT;                                                                 \
        TAIL_STMT;                                                                  \
        __builtin_amdgcn_s_barrier();                                               \
        asm volatile("s_waitcnt lgkmcnt(0)" ::: "memory");                          \
        __builtin_amdgcn_sched_barrier(0);                                          \
        __builtin_amdgcn_s_setprio(1);                                              \
        if (wact) {                                                                 \
            _Pragma("unroll")                                                       \
            for (int m2 = 0; m2 < 2; ++m2)                                          \
                _Pragma("unroll")                                                   \
                for (int ks = 0; ks < 2; ++ks)                                      \
                    _Pragma("unroll")                                               \
                    for (int nj = 0; nj < 4; ++nj)                                  \
                        acc[((Q) << 1) | m2][nj] =                                  \
                            __builtin_amdgcn_mfma_f32_16x16x32_bf16(                \
                                bq[nj][ks], af[m2][ks],                             \
                                acc[((Q) << 1) | m2][nj], 0, 0, 0);                 \
        }                                                                           \
        __builtin_amdgcn_s_setprio(0);                                              \
    } while (0)

    for (int tau = 0; tau < nt; tau += 2) {
        // ---- tile tau (buf 0) ----   (tau+1 <= nt-1 always)
        PHASE(0, 0, { STA(1, 0, tau + 1); }, {});
        PHASE(0, 1, { STA(1, 1, tau + 1); }, {});
        PHASE(0, 2, { if (tau + 2 < nt) STB(0, 0, tau + 2); }, {});
        PHASE(0, 3, { if (tau + 2 < nt) STB(0, 1, tau + 2); },
                    { if (tau + 2 < nt) asm volatile("s_waitcnt vmcnt(4)" ::: "memory");
                      else               asm volatile("s_waitcnt vmcnt(0)" ::: "memory"); });
        // ---- tile tau+1 (buf 1) ----
        PHASE(1, 0, { if (tau + 2 < nt) STA(0, 0, tau + 2); }, {});
        PHASE(1, 1, { if (tau + 2 < nt) STA(0, 1, tau + 2); }, {});
        PHASE(1, 2, { if (tau + 3 < nt) STB(1, 0, tau + 3); }, {});
        PHASE(1, 3, { if (tau + 3 < nt) STB(1, 1, tau + 3); },
                    { if (tau + 3 < nt)      asm volatile("s_waitcnt vmcnt(4)" ::: "memory");
                      else if (tau + 2 < nt) asm volatile("s_waitcnt vmcnt(0)" ::: "memory"); });
    }
#undef PHASE
#undef STA
#undef STB

    if (!wact) return;
    // epilogue: lane m = frow; n = n0 + wc*64 + nj*16 + fks*4 + r
    #pragma unroll
    for (int mi = 0; mi < 8; ++mi) {
        const long row = m0 + (wr << 7) + (mi << 4) + frow;
        #pragma unroll
        for (int nj = 0; nj < 4; ++nj) {
            const int n = (int)n0 + (wc << 6) + (nj << 4) + (fks << 2);
            if (n >= ncb) continue;
            f32x4 v = acc[mi][nj];
            if (bias) v += *(const f32x4*)&bias[n];
            if (act_gelu) {
                v[0] = gelu_f(v[0]); v[1] = gelu_f(v[1]); v[2] = gelu_f(v[2]); v[3] = gelu_f(v[3]);
            }
            const long base = row * (long)ldb + col_off + n;
            if (resid) {
                const short4 rv = *(const short4*)&resid[base];
                v[0] += bf2f(rv.x); v[1] += bf2f(rv.y);
                v[2] += bf2f(rv.z); v[3] += bf2f(rv.w);
            }
            short4 p;
            p.x = f2bf(v[0]); p.y = f2bf(v[1]); p.z = f2bf(v[2]); p.w = f2bf(v[3]);
            *(short4*)&Cb[base] = p;
        }
    }
}

// ===== 128x128 GEMM (kept for final conv: fp32 NCHW scatter) =====
__global__ __launch_bounds__(256, 3)
void gemm128_kernel(const __hip_bfloat16* __restrict__ A,
                    const __hip_bfloat16* __restrict__ Bt,
                    const float* __restrict__ bias,
                    float* __restrict__ Cf,
                    int K, int nvalid) {
    extern __shared__ __align__(16) char smraw[];   // 2 x 16384B: [A 8192 | B 8192]

    const int tid  = threadIdx.x;
    const int lane = tid & 63;
    const int wv   = tid >> 6;
    const int wr   = wv >> 1;
    const int wc   = wv & 1;

    const int gx   = gridDim.x;
    const int nwg  = gx * gridDim.y;
    const int orig = blockIdx.y * gx + blockIdx.x;
    const int qq = nwg >> 3, rr = nwg & 7;
    const int xcd = orig & 7, lid = orig >> 3;
    const int wg = (xcd < rr ? xcd * (qq + 1) : rr * (qq + 1) + (xcd - rr) * qq) + lid;
    const long m0 = (long)(wg / gx) * 128;
    const long n0 = (long)(wg % gx) * 128;

    const bool wact = ((int)n0 + (wc << 6)) < nvalid;

    f32x4 acc[4][4];
    #pragma unroll
    for (int i = 0; i < 4; i++)
        #pragma unroll
        for (int j = 0; j < 4; j++) acc[i][j] = (f32x4){0.f, 0.f, 0.f, 0.f};

    const int r0  = tid >> 2;
    const int sl  = tid & 3;
    const int ssl = sl ^ ((r0 >> 1) & 3);
    const __hip_bfloat16* Agb = A  + (m0 + r0) * (long)K + (ssl << 3);
    const __hip_bfloat16* Bgb = Bt + (n0 + r0) * (long)K + (ssl << 3);
    char* dA = smraw + r0 * 64 + sl * 16;
    char* dB = dA + 8192;

    const int frow = lane & 15;
    const int fks  = lane >> 4;
    const int colA = (fks ^ ((frow >> 1) & 3)) << 4;

    auto STAGE = [&](int boff, int kt) {
        const long ko = (long)kt << 5;
        gload_lds16(Agb + ko,                dA + boff);
        gload_lds16(Agb + 64 * (long)K + ko, dA + boff + 4096);
        gload_lds16(Bgb + ko,                dB + boff);
        gload_lds16(Bgb + 64 * (long)K + ko, dB + boff + 4096);
    };

#define COMPUTE(BUFOFF)                                                                     \
    do {                                                                                    \
        if (wact) {                                                                         \
            const char* pA = smraw + (BUFOFF);                                              \
            const char* pB = pA + 8192;                                                     \
            short8 af[4], bfr[4];                                                           \
            _Pragma("unroll")                                                               \
            for (int mi = 0; mi < 4; ++mi)                                                  \
                af[mi] = *(const short8*)(pA + ((wr << 6) + (mi << 4) + frow) * 64 + colA); \
            _Pragma("unroll")                                                               \
            for (int nj = 0; nj < 4; ++nj)                                                  \
                bfr[nj] = *(const short8*)(pB + ((wc << 6) + (nj << 4) + frow) * 64 + colA);\
            __builtin_amdgcn_s_setprio(1);                                                  \
            _Pragma("unroll")                                                               \
            for (int mi = 0; mi < 4; ++mi)                                                  \
                _Pragma("unroll")                                                           \
                for (int nj = 0; nj < 4; ++nj)                                              \
                    acc[mi][nj] = __builtin_amdgcn_mfma_f32_16x16x32_bf16(                  \
                        bfr[nj], af[mi], acc[mi][nj], 0, 0, 0);                             \
            __builtin_amdgcn_s_setprio(0);                                                  \
        }                                                                                   \
    } while (0)

    const int nt = K >> 5;
    STAGE(0, 0);
    for (int t = 0; t < nt; t += 2) {
        asm volatile("s_waitcnt vmcnt(0)" ::: "memory");
        __builtin_amdgcn_s_barrier();
        __builtin_amdgcn_sched_barrier(0);
        if (t + 1 < nt) STAGE(16384, t + 1);
        COMPUTE(0);
        asm volatile("s_waitcnt vmcnt(0)" ::: "memory");
        __builtin_amdgcn_s_barrier();
        __builtin_amdgcn_sched_barrier(0);
        if (t + 2 < nt) STAGE(0, t + 2);
        COMPUTE(16384);
    }
#undef COMPUTE

    if (!wact) return;
    #pragma unroll
    for (int mi = 0; mi < 4; ++mi) {
        const long row = m0 + (wr << 6) + (mi << 4) + frow;
        #pragma unroll
        for (int nj = 0; nj < 4; ++nj) {
            const int n = (int)n0 + (wc << 6) + (nj << 4) + (fks << 2);
            if (n >= nvalid) continue;
            f32x4 v = acc[mi][nj];
            if (bias) v += *(const f32x4*)&bias[n];
            // NCHW scatter: out[(b*64 + n+r)*3136 + pos], row = b*3136 + pos
            const int b = (int)(row / 3136), pos = (int)(row % 3136);
            #pragma unroll
            for (int r = 0; r < 4; ++r)
                Cf[(long)(b * 64 + n + r) * 3136 + pos] = v[r];
        }
    }
}

// ---------------- window attention (per window-head, fp32 in LDS) ----------------
__global__ __launch_bounds__(256)
void attn_kernel(const __hip_bfloat16* __restrict__ qkv, __hip_bfloat16* __restrict__ o,
                 int shift) {
    __shared__ __align__(16) float qT[80][52];
    __shared__ __align__(16) float kT[80][52];
    __shared__ __align__(16) float vs[50][80];
    __shared__ __align__(16) float ss[49][52];
    __shared__ int toks[49];
    __shared__ int rid[49];

    const int tid = threadIdx.x;
    const int win = blockIdx.x >> 3;
    const int hd  = blockIdx.x & 7;
    const int b   = win >> 6;
    const int wh  = (win >> 3) & 7;
    const int ww  = win & 7;

    if (tid < 49) {
        int i = tid / 7, j = tid % 7;
        int ph = wh * 7 + i, pw = ww * 7 + j;
        int sh = ph + shift; if (sh >= 56) sh -= 56;
        int sw = pw + shift; if (sw >= 56) sw -= 56;
        toks[tid] = (b * 56 + sh) * 56 + sw;
        int rh = (ph < 49) ? 0 : ((ph < 53) ? 1 : 2);
        int rw = (pw < 49) ? 0 : ((pw < 53) ? 1 : 2);
        rid[tid] = rh * 3 + rw;
    }
    for (int i = tid; i < 80 * 3; i += 256) {
        int d = i / 3, cc = 49 + (i % 3);
        qT[d][cc] = 0.f; kT[d][cc] = 0.f;
    }
    __syncthreads();
    for (int idx = tid; idx < 49 * 80; idx += 256) {
        int t = idx / 80, d = idx % 80;
        long base = (long)toks[t] * 1920 + hd * 80 + d;
        qT[d][t] = __bfloat162float(qkv[base]);
        kT[d][t] = __bfloat162float(qkv[base + 640]);
        vs[t][d] = __bfloat162float(qkv[base + 1280]);
    }
    __syncthreads();
    const float scale = 0.11180339887498948f;
    for (int p = tid; p < 49 * 13; p += 256) {
        int t = p / 13, j0 = (p % 13) * 4;
        float4 a = {0.f, 0.f, 0.f, 0.f};
        #pragma unroll
        for (int d = 0; d < 80; d++) {
            float qv = qT[d][t];
            float4 kv = *(const float4*)&kT[d][j0];
            a.x += qv * kv.x; a.y += qv * kv.y; a.z += qv * kv.z; a.w += qv * kv.w;
        }
        a.x *= scale; a.y *= scale; a.z *= scale; a.w *= scale;
        *(float4*)&ss[t][j0] = a;
    }
    __syncthreads();
    if (tid < 196) {
        const int r = tid >> 2, sub = tid & 3;
        const int j0 = sub * 13;
        const int j1 = (sub == 3) ? 10 : 13;
        const int myr = rid[r];
        float mx = -1e30f;
        for (int i = 0; i < j1; i++) {
            float v = ss[r][j0 + i];
            if (shift && rid[j0 + i] != myr) v = -1e9f;
            ss[r][j0 + i] = v;
            mx = fmaxf(mx, v);
        }
        mx = fmaxf(mx, __shfl_xor(mx, 1));
        mx = fmaxf(mx, __shfl_xor(mx, 2));
        float sum = 0.f;
        for (int i = 0; i < j1; i++) {
            float e = __expf(ss[r][j0 + i] - mx);
            ss[r][j0 + i] = e;
            sum += e;
        }
        sum += __shfl_xor(sum, 1);
        sum += __shfl_xor(sum, 2);
        const float inv = 1.f / sum;
        for (int i = 0; i < j1; i++) ss[r][j0 + i] *= inv;
    }
    __syncthreads();
    for (int p = tid; p < 49 * 20; p += 256) {
        int t = p / 20, dv = (p % 20) * 4;
        float4 a = {0.f, 0.f, 0.f, 0.f};
        for (int j = 0; j < 49; j++) {
            float w = ss[t][j];
            float4 vv = *(const float4*)&vs[j][dv];
            a.x += w * vv.x; a.y += w * vv.y; a.z += w * vv.z; a.w += w * vv.w;
        }
        long base = (long)toks[t] * DD + hd * 80 + dv;
        o[base + 0] = __float2bfloat16(a.x);
        o[base + 1] = __float2bfloat16(a.y);
        o[base + 2] = __float2bfloat16(a.z);
        o[base + 3] = __float2bfloat16(a.w);
    }
}

// ---- inverse NSCT: reads bf16 y-mirror (ayc cols [64,640)), writes ayc cols [0,64) ----
__global__ __launch_bounds__(256)
void ict_kernel(__hip_bfloat16* ayc, const float* __restrict__ filt) {
    __shared__ float sf[225];
    for (int i = threadIdx.x; i < 225; i += 256) sf[i] = filt[i];
    __syncthreads();
    int id = blockIdx.x * 256 + threadIdx.x;   // NTOK * 16
    int c4 = (id & 15) << 2;
    int pix = id >> 4;
    int w = pix % 56, h = (pix / 56) % 56, b = pix / 3136;
    float4 a = {0.f, 0.f, 0.f, 0.f};
    #pragma unroll
    for (int dy = 0; dy < 5; dy++) {
        int hy = h + dy - 2;
        if (hy < 0 || hy >= 56) continue;
        #pragma unroll
        for (int dx = 0; dx < 5; dx++) {
            int wx = w + dx - 2;
            if (wx < 0 || wx >= 56) continue;
            const __hip_bfloat16* yr = ayc + ((long)(b * 56 + hy) * 56 + wx) * DD + 64 + c4;
            #pragma unroll
            for (int band = 0; band < 9; band++) {
                const float f = sf[band*25 + dy*5 + dx];
                const short4 sv = *(const short4*)&yr[band * 64];
                a.x += bf2f(sv.x) * f; a.y += bf2f(sv.y) * f;
                a.z += bf2f(sv.z) * f; a.w += bf2f(sv.w) * f;
            }
        }
    }
    short4 p;
    p.x = f2bf(a.x); p.y = f2bf(a.y); p.z = f2bf(a.z); p.w = f2bf(a.w);
    *(short4*)&ayc[(long)pix * DD + c4] = p;
}

// ---------------- host ----------------
extern "C" void kernel_launch(void* const* d_in, const int* in_sizes, int n_in,
                              void* d_out, int out_size, void* d_ws, size_t ws_size,
                              hipStream_t stream) {
    (void)in_sizes; (void)n_in; (void)out_size; (void)ws_size;
    const float* x      = (const float*)d_in[0];
    const float* ln1_g  = (const float*)d_in[1];
    const float* ln1_b  = (const float*)d_in[2];
    const float* qkv_w  = (const float*)d_in[3];
    const float* qkv_b  = (const float*)d_in[4];
    const float* proj_w = (const float*)d_in[5];
    const float* proj_b = (const float*)d_in[6];
    const float* ln2_g  = (const float*)d_in[7];
    const float* ln2_b  = (const float*)d_in[8];
    const float* fc1_w  = (const float*)d_in[9];
    const float* fc1_b  = (const float*)d_in[10];
    const float* fc2_w  = (const float*)d_in[11];
    const float* fc2_b  = (const float*)d_in[12];
    const float* lin_w  = (const float*)d_in[13];
    const float* lin_b  = (const float*)d_in[14];
    const float* conv_w = (const float*)d_in[15];
    const float* conv_b = (const float*)d_in[16];

    char* ws = (char*)d_ws;
    size_t off = 0;
    auto alloc = [&](size_t bytes) -> void* {
        void* p = ws + off;
        off += (bytes + 255) & ~(size_t)255;
        return p;
    };
    float* filt   = (float*)alloc(225 * 4);
    float* linbp  = (float*)alloc(640 * 4);
    float* convbp = (float*)alloc(128 * 4);
    // B-row padding to 256 multiples for the 256-tile kernel
    __hip_bfloat16* qkvWt[2], *projWt[2], *fc1Wt[2], *fc2Wt[2];
    for (int i = 0; i < 2; i++) qkvWt[i] = (__hip_bfloat16*)alloc(2048L * 640 * 2);
    for (int i = 0; i < 2; i++) projWt[i] = (__hip_bfloat16*)alloc(768L * 640 * 2);
    for (int i = 0; i < 2; i++) fc1Wt[i] = (__hip_bfloat16*)alloc(2560L * 640 * 2);
    for (int i = 0; i < 2; i++) fc2Wt[i] = (__hip_bfloat16*)alloc(768L * 2560 * 2);
    __hip_bfloat16* linWt  = (__hip_bfloat16*)alloc(768L * 640 * 2);
    __hip_bfloat16* convWt = (__hip_bfloat16*)alloc(128L * 640 * 2);   // 128 rows (gemm128)
    __hip_bfloat16* x3   = (__hip_bfloat16*)alloc((long)NTOK * DD * 2);
    __hip_bfloat16* bufA = (__hip_bfloat16*)alloc((long)NTOK * DD * 2);
    char* bufB = (char*)alloc((long)NTOK * 2560 * 2);
    __hip_bfloat16* qkv = (__hip_bfloat16*)bufB;
    __hip_bfloat16* h2  = (__hip_bfloat16*)bufB;
    __hip_bfloat16* ayc = (__hip_bfloat16*)(bufB + (long)NTOK * DD * 4);

    hipFuncSetAttribute((const void*)gemm8p_kernel,
                        hipFuncAttributeMaxDynamicSharedMemorySize, 131072);
    hipFuncSetAttribute((const void*)gemm128_kernel,
                        hipFuncAttributeMaxDynamicSharedMemorySize, 32768);

    dim3 tb(32, 8);
    init_consts<<<1, 256, 0, stream>>>(filt, linbp, lin_b, convbp, conv_b);
    for (int i = 0; i < 2; i++) {
        wtrans_kernel<<<dim3(64, 20), tb, 0, stream>>>(qkv_w + (long)i*640*1920, qkvWt[i], 640, 1920);
        wtrans_kernel<<<dim3(24, 20), tb, 0, stream>>>(proj_w + (long)i*640*640,  projWt[i], 640, 640);
        wtrans_kernel<<<dim3(80, 20), tb, 0, stream>>>(fc1_w + (long)i*640*2560, fc1Wt[i], 640, 2560);
        wtrans_kernel<<<dim3(24, 80), tb, 0, stream>>>(fc2_w + (long)i*2560*640, fc2Wt[i], 2560, 640);
    }
    wtrans_kernel<<<dim3(24, 20), tb, 0, stream>>>(lin_w, linWt, 640, 576);
    wcast_kernel<<<320, 256, 0, stream>>>(conv_w, convWt, 64 * 640, 128 * 640);

    // prep: writes x3 bf16 + fused LN1(layer0) bf16 into bufA
    prep_kernel<<<6272, 256, 0, stream>>>(x, filt, x3, ln1_g, ln1_b, bufA);

    for (int i = 0; i < 2; i++) {
        int shift = i ? 3 : 0;
        if (i == 1)
            ln_kernel<<<6272, 256, 0, stream>>>(x3, ln1_g + i*640, ln1_b + i*640, bufA);
        // qkv: Npad=2048 (gx=8), valid 1920
        gemm8p_kernel<<<dim3(8, 98), 512, 131072, stream>>>(bufA, qkvWt[i], qkv_b + i*1920,
            nullptr, qkv, 640, 1920, 0, 1920, 0, 1920);
        attn_kernel<<<4096, 256, 0, stream>>>(qkv, bufA, shift);
        // proj: Npad=768 (gx=3), valid 640, resid+out = x3
        gemm8p_kernel<<<dim3(3, 98), 512, 131072, stream>>>(bufA, projWt[i], proj_b + i*640,
            x3, x3, 640, 640, 0, 640, 0, 640);
        ln_kernel<<<6272, 256, 0, stream>>>(x3, ln2_g + i*640, ln2_b + i*640, bufA);
        // fc1: N=2560 (gx=10), gelu
        gemm8p_kernel<<<dim3(10, 98), 512, 131072, stream>>>(bufA, fc1Wt[i], fc1_b + i*2560,
            nullptr, h2, 640, 2560, 0, 2560, 1, 2560);
        // fc2: Npad=768, K=2560, resid+out = x3
        gemm8p_kernel<<<dim3(3, 98), 512, 131072, stream>>>(h2, fc2Wt[i], fc2_b + i*640,
            x3, x3, 2560, 640, 0, 640, 0, 640);
    }
    // lin: Npad=768, bf16 out into ayc cols [64,640)
    gemm8p_kernel<<<dim3(3, 98), 512, 131072, stream>>>(x3, linWt, linbp,
        nullptr, ayc, 640, 640, 64, 576, 0, 576);
    ict_kernel<<<1568, 256, 0, stream>>>(ayc, filt);   // fills ayc cols [0,64)
    // conv: N=128 (64 valid), direct NCHW store into d_out (fuses unpack)
    gemm128_kernel<<<dim3(1, 196), 256, 32768, stream>>>(ayc, convWt, convbp,
        (float*)d_out, 640, 64);
}

// Round 18
// 1290.480 us; speedup vs baseline: 4.0720x; 4.0720x over previous
//
#include <hip/hip_runtime.h>
#include <hip/hip_bf16.h>
#include <math.h>

// ---------------- types ----------------
typedef __attribute__((ext_vector_type(4))) float f32x4;
typedef __attribute__((ext_vector_type(8))) short short8;

#define NTOK 25088   // B*H*W = 8*56*56
#define DD   640

__device__ __forceinline__ void gload_lds16(const void* g, void* l) {
    __builtin_amdgcn_global_load_lds((const __attribute__((address_space(1))) void*)g,
                                     (__attribute__((address_space(3))) void*)l,
                                     16, 0, 0);
}

// exact rewrite of tanh-gelu: 0.5t(1+tanh(v)) = t * sigmoid(2v)
__device__ __forceinline__ float gelu_f(float t) {
    float u = 1.5957691216057308f * (t + 0.044715f * t * t * t);
    float e = __builtin_amdgcn_exp2f(u * -1.4426950408889634f);   // exp(-u)
    return t / (1.f + e);
}

__device__ __forceinline__ float bf2f(short u) {
    union { unsigned int i; float f; } cv;
    cv.i = ((unsigned int)(unsigned short)u) << 16;
    return cv.f;
}
__device__ __forceinline__ short f2bf(float f) {
    return (short)__bfloat16_as_short(__float2bfloat16(f));
}

// ---------------- constants init: NSCT filters + padded biases ----------------
__global__ void init_consts(float* __restrict__ filt, float* __restrict__ linbp,
                            const float* __restrict__ lin_b, float* __restrict__ convbp,
                            const float* __restrict__ conv_b) {
    int t = threadIdx.x;
    if (t == 0) {
        float g[25]; float s = 0.f;
        for (int i = 0; i < 5; i++) for (int j = 0; j < 5; j++) {
            float yy = (float)(i - 2), xx = (float)(j - 2);
            float v = expf(-(xx*xx + yy*yy) * 0.25f);
            g[i*5+j] = v; s += v;
        }
        for (int i = 0; i < 25; i++) { g[i] /= s; filt[i] = g[i]; }
        for (int k = 0; k < 8; k++) {
            float th = (float)k * 3.14159265358979323846f / 8.f;
            float ct = cosf(th), st = sinf(th);
            float d[25]; float mean = 0.f;
            for (int i = 0; i < 5; i++) for (int j = 0; j < 5; j++) {
                float yy = (float)(i - 2), xx = (float)(j - 2);
                d[i*5+j] = (ct*xx + st*yy) * g[i*5+j];
                mean += d[i*5+j];
            }
            mean *= (1.f/25.f);
            float ss = 0.f;
            for (int i = 0; i < 25; i++) { d[i] -= mean; ss += d[i]*d[i]; }
            ss = sqrtf(ss);
            for (int i = 0; i < 25; i++) filt[(k+1)*25 + i] = d[i] / ss;
        }
    }
    for (int i = t; i < 640; i += 256) linbp[i]  = (i < 576) ? lin_b[i]  : 0.f;
    for (int i = t; i < 128; i += 256) convbp[i] = (i < 64)  ? conv_b[i] : 0.f;
}

// ---------------- weight transpose+cast: dst[n][k] = bf16(src[k][n]), zero-pad n>=Nsrc ----------------
__global__ __launch_bounds__(256)
void wtrans_kernel(const float* __restrict__ src, __hip_bfloat16* __restrict__ dst,
                   int K, int Nsrc) {
    __shared__ float tile[32][33];
    const int n0 = blockIdx.x * 32;
    const int k0 = blockIdx.y * 32;
    const int tx = threadIdx.x, ty = threadIdx.y;
    #pragma unroll
    for (int r = ty; r < 32; r += 8) {
        int k = k0 + r, n = n0 + tx;
        tile[r][tx] = (n < Nsrc) ? src[(long)k * Nsrc + n] : 0.f;
    }
    __syncthreads();
    #pragma unroll
    for (int r = ty; r < 32; r += 8) {
        int n = n0 + r, k = k0 + tx;
        dst[(long)n * K + k] = __float2bfloat16(tile[tx][r]);
    }
}

__global__ void wcast_kernel(const float* __restrict__ src, __hip_bfloat16* __restrict__ dst,
                             int count, int total) {
    int i = blockIdx.x * 256 + threadIdx.x;
    if (i < total) dst[i] = __float2bfloat16(i < count ? src[i] : 0.f);
}

// ---- prep: relu + 9-band NSCT conv + concat -> x3 bf16 AND fused LN1(layer0) -> bufA bf16 ----
__global__ __launch_bounds__(256)
void prep_kernel(const float* __restrict__ x, const float* __restrict__ filt,
                 __hip_bfloat16* __restrict__ x3, const float* __restrict__ g1,
                 const float* __restrict__ b1, __hip_bfloat16* __restrict__ lnout) {
    __shared__ float sf[225];
    for (int i = threadIdx.x; i < 225; i += 256) sf[i] = filt[i];
    __syncthreads();
    int id = blockIdx.x * 256 + threadIdx.x;   // B*H*W*C
    int c = id & 63;
    int pix = id >> 6;
    int w = pix % 56, h = (pix / 56) % 56, b = pix / 3136;
    const float* xp = x + (long)(b * 64 + c) * 3136;
    float nb[25];
    #pragma unroll
    for (int dy = 0; dy < 5; dy++) {
        int hy = h + dy - 2;
        #pragma unroll
        for (int dx = 0; dx < 5; dx++) {
            int wx = w + dx - 2;
            float v = 0.f;
            if (hy >= 0 && hy < 56 && wx >= 0 && wx < 56) v = fmaxf(xp[hy*56 + wx], 0.f);
            nb[dy*5 + dx] = v;
        }
    }
    float bo[9];
    __hip_bfloat16* orow = x3 + (long)pix * DD;
    float s = 0.f, s2 = 0.f;
    #pragma unroll
    for (int band = 0; band < 9; band++) {
        float a = 0.f;
        #pragma unroll
        for (int t = 0; t < 25; t++) a += nb[t] * sf[band*25 + t];
        bo[band] = a;
        orow[band*64 + c] = __float2bfloat16(a);
        s += a; s2 += a * a;
    }
    const float ctr = nb[12];
    orow[576 + c] = __float2bfloat16(ctr);     // relu(x) center copy
    s += ctr; s2 += ctr * ctr;
    // wave-wide LN (this wave == this pixel's 64 channels x 10 vals)
    #pragma unroll
    for (int o = 32; o > 0; o >>= 1) { s += __shfl_xor(s, o); s2 += __shfl_xor(s2, o); }
    const float mean = s * (1.f/640.f);
    const float var  = s2 * (1.f/640.f) - mean * mean;
    const float inv  = 1.f / sqrtf(var + 1e-5f);
    __hip_bfloat16* ob = lnout + (long)pix * DD;
    #pragma unroll
    for (int band = 0; band < 9; band++) {
        int ci = band*64 + c;
        ob[ci] = __float2bfloat16((bo[band] - mean) * inv * g1[ci] + b1[ci]);
    }
    ob[576 + c] = __float2bfloat16((ctr - mean) * inv * g1[576 + c] + b1[576 + c]);
}

// ---------------- LayerNorm (per-token over 640, bf16 in) -> bf16 ----------------
__global__ __launch_bounds__(256)
void ln_kernel(const __hip_bfloat16* __restrict__ xin, const float* __restrict__ g,
               const float* __restrict__ bt, __hip_bfloat16* __restrict__ out) {
    const int lane = threadIdx.x & 63;
    const long tok = (long)blockIdx.x * 4 + (threadIdx.x >> 6);
    const __hip_bfloat16* xr = xin + tok * DD;
    float v[10]; float s = 0.f, s2 = 0.f;
    #pragma unroll
    for (int i = 0; i < 10; i++) {
        float t = __bfloat162float(xr[lane + (i << 6)]);
        v[i] = t; s += t; s2 += t*t;
    }
    #pragma unroll
    for (int o = 32; o > 0; o >>= 1) { s += __shfl_xor(s, o); s2 += __shfl_xor(s2, o); }
    const float mean = s * (1.f/640.f);
    const float var  = s2 * (1.f/640.f) - mean * mean;
    const float inv  = 1.f / sqrtf(var + 1e-5f);
    __hip_bfloat16* orow = out + tok * DD;
    #pragma unroll
    for (int i = 0; i < 10; i++) {
        int c = lane + (i << 6);
        orow[c] = __float2bfloat16((v[i] - mean) * inv * g[c] + bt[c]);
    }
}

// ===== 128x128 GEMM, BK=32, double-buffer 32KB, 4 blocks/CU, K-loop unrolled x2 =====
// C = A @ Bt^T + bias [+gelu] [+bf16 resid]; bf16 out (mode 0) or fp32 NCHW scatter (mode 1).
// __launch_bounds__(256,3): reg budget 170, no spill (R11 lesson); runtime occupancy 4 blk/CU
// (128-reg granule caps at 4 waves/SIMD). Swizzle: 16B slot ^= (row>>1)&3 on global source
// + LDS read (rule #21, 0 conflicts). One vmcnt(0)+barrier per K-tile; STAGE(t+1) overlaps.
__global__ __launch_bounds__(256, 3)
void gemm128_kernel(const __hip_bfloat16* __restrict__ A,
                    const __hip_bfloat16* __restrict__ Bt,
                    const float* __restrict__ bias,
                    const __hip_bfloat16* __restrict__ resid,
                    float* __restrict__ Cf,
                    __hip_bfloat16* __restrict__ Cb,
                    int K, int ldb, int col_off, int ncb,
                    int act_gelu, int nvalid, int mode) {
    extern __shared__ __align__(16) char smraw[];   // 2 x 16384B: [A 8192 | B 8192]

    const int tid  = threadIdx.x;
    const int lane = tid & 63;
    const int wv   = tid >> 6;
    const int wr   = wv >> 1;          // 0..1  (M half: 64 rows)
    const int wc   = wv & 1;           // 0..1  (N half: 64 cols)

    // ---- bijective XCD-aware block remap (m204) ----
    const int gx   = gridDim.x;
    const int nwg  = gx * gridDim.y;
    const int orig = blockIdx.y * gx + blockIdx.x;
    const int qq = nwg >> 3, rr = nwg & 7;
    const int xcd = orig & 7, lid = orig >> 3;
    const int wg = (xcd < rr ? xcd * (qq + 1) : rr * (qq + 1) + (xcd - rr) * qq) + lid;
    const long m0 = (long)(wg / gx) * 128;
    const long n0 = (long)(wg % gx) * 128;

    const bool wact = ((int)n0 + (wc << 6)) < nvalid;

    f32x4 acc[4][4];
    #pragma unroll
    for (int i = 0; i < 4; i++)
        #pragma unroll
        for (int j = 0; j < 4; j++) acc[i][j] = (f32x4){0.f, 0.f, 0.f, 0.f};

    // staging: per K-tile(32) each matrix tile is 8KB = 2 x (256 thr x 16B)
    const int r0  = tid >> 2;
    const int sl  = tid & 3;
    const int ssl = sl ^ ((r0 >> 1) & 3);
    const __hip_bfloat16* Agb = A  + (m0 + r0) * (long)K + (ssl << 3);
    const __hip_bfloat16* Bgb = Bt + (n0 + r0) * (long)K + (ssl << 3);
    char* dA = smraw + r0 * 64 + sl * 16;            // linear LDS dest
    char* dB = dA + 8192;

    const int frow = lane & 15;
    const int fks  = lane >> 4;                      // 0..3 (k-slot within K=32)
    const int colA = (fks ^ ((frow >> 1) & 3)) << 4; // swizzled 16B slot -> byte offset

    auto STAGE = [&](int boff, int kt) {
        const long ko = (long)kt << 5;
        gload_lds16(Agb + ko,                dA + boff);
        gload_lds16(Agb + 64 * (long)K + ko, dA + boff + 4096);
        gload_lds16(Bgb + ko,                dB + boff);
        gload_lds16(Bgb + 64 * (long)K + ko, dB + boff + 4096);
    };

#define COMPUTE(BUFOFF)                                                                     \
    do {                                                                                    \
        if (wact) {                                                                         \
            const char* pA = smraw + (BUFOFF);                                              \
            const char* pB = pA + 8192;                                                     \
            short8 af[4], bfr[4];                                                           \
            _Pragma("unroll")                                                               \
            for (int mi = 0; mi < 4; ++mi)                                                  \
                af[mi] = *(const short8*)(pA + ((wr << 6) + (mi << 4) + frow) * 64 + colA); \
            _Pragma("unroll")                                                               \
            for (int nj = 0; nj < 4; ++nj)                                                  \
                bfr[nj] = *(const short8*)(pB + ((wc << 6) + (nj << 4) + frow) * 64 + colA);\
            __builtin_amdgcn_s_setprio(1);                                                  \
            _Pragma("unroll")                                                               \
            for (int mi = 0; mi < 4; ++mi)                                                  \
                _Pragma("unroll")                                                           \
                for (int nj = 0; nj < 4; ++nj)  /* SWAPPED: D rows <- N, cols <- M */       \
                    acc[mi][nj] = __builtin_amdgcn_mfma_f32_16x16x32_bf16(                  \
                        bfr[nj], af[mi], acc[mi][nj], 0, 0, 0);                             \
            __builtin_amdgcn_s_setprio(0);                                                  \
        }                                                                                   \
    } while (0)

    const int nt = K >> 5;                           // EVEN at all call sites (20, 80)
    STAGE(0, 0);
    for (int t = 0; t < nt; t += 2) {
        asm volatile("s_waitcnt vmcnt(0)" ::: "memory");   // tile t landed (own loads)
        __builtin_amdgcn_s_barrier();
        __builtin_amdgcn_sched_barrier(0);
        if (t + 1 < nt) STAGE(16384, t + 1);
        COMPUTE(0);
        asm volatile("s_waitcnt vmcnt(0)" ::: "memory");   // tile t+1 landed
        __builtin_amdgcn_s_barrier();
        __builtin_amdgcn_sched_barrier(0);
        if (t + 2 < nt) STAGE(0, t + 2);
        COMPUTE(16384);
    }
#undef COMPUTE

    if (!wact) return;
    // epilogue: lane holds m = frow (fixed), n = base + fks*4 + r  (4 consecutive cols)
    #pragma unroll
    for (int mi = 0; mi < 4; ++mi) {
        const long row = m0 + (wr << 6) + (mi << 4) + frow;
        #pragma unroll
        for (int nj = 0; nj < 4; ++nj) {
            const int n = (int)n0 + (wc << 6) + (nj << 4) + (fks << 2);
            if (n >= ncb) continue;
            f32x4 v = acc[mi][nj];
            if (bias) {
                const f32x4 bv = *(const f32x4*)&bias[n];
                v += bv;
            }
            if (act_gelu) {
                v[0] = gelu_f(v[0]); v[1] = gelu_f(v[1]); v[2] = gelu_f(v[2]); v[3] = gelu_f(v[3]);
            }
            if (mode == 1) {
                // NCHW scatter: out[(b*64 + n+r)*3136 + pos], row = b*3136 + pos
                const int b = (int)(row / 3136), pos = (int)(row % 3136);
                #pragma unroll
                for (int r = 0; r < 4; ++r)
                    Cf[(long)(b * 64 + n + r) * 3136 + pos] = v[r];
                continue;
            }
            const long base = row * (long)ldb + col_off + n;
            if (resid) {
                const short4 rv = *(const short4*)&resid[base];
                v[0] += bf2f(rv.x); v[1] += bf2f(rv.y);
                v[2] += bf2f(rv.z); v[3] += bf2f(rv.w);
            }
            short4 p;
            p.x = f2bf(v[0]); p.y = f2bf(v[1]); p.z = f2bf(v[2]); p.w = f2bf(v[3]);
            *(short4*)&Cb[base] = p;
        }
    }
}

// ---------------- window attention (per window-head, fp32 in LDS) ----------------
__global__ __launch_bounds__(256)
void attn_kernel(const __hip_bfloat16* __restrict__ qkv, __hip_bfloat16* __restrict__ o,
                 int shift) {
    __shared__ __align__(16) float qT[80][52];
    __shared__ __align__(16) float kT[80][52];
    __shared__ __align__(16) float vs[50][80];
    __shared__ __align__(16) float ss[49][52];
    __shared__ int toks[49];
    __shared__ int rid[49];

    const int tid = threadIdx.x;
    const int win = blockIdx.x >> 3;
    const int hd  = blockIdx.x & 7;
    const int b   = win >> 6;
    const int wh  = (win >> 3) & 7;
    const int ww  = win & 7;

    if (tid < 49) {
        int i = tid / 7, j = tid % 7;
        int ph = wh * 7 + i, pw = ww * 7 + j;
        int sh = ph + shift; if (sh >= 56) sh -= 56;
        int sw = pw + shift; if (sw >= 56) sw -= 56;
        toks[tid] = (b * 56 + sh) * 56 + sw;
        int rh = (ph < 49) ? 0 : ((ph < 53) ? 1 : 2);
        int rw = (pw < 49) ? 0 : ((pw < 53) ? 1 : 2);
        rid[tid] = rh * 3 + rw;
    }
    for (int i = tid; i < 80 * 3; i += 256) {
        int d = i / 3, cc = 49 + (i % 3);
        qT[d][cc] = 0.f; kT[d][cc] = 0.f;
    }
    __syncthreads();
    for (int idx = tid; idx < 49 * 80; idx += 256) {
        int t = idx / 80, d = idx % 80;
        long base = (long)toks[t] * 1920 + hd * 80 + d;
        qT[d][t] = __bfloat162float(qkv[base]);
        kT[d][t] = __bfloat162float(qkv[base + 640]);
        vs[t][d] = __bfloat162float(qkv[base + 1280]);
    }
    __syncthreads();
    const float scale = 0.11180339887498948f;
    for (int p = tid; p < 49 * 13; p += 256) {
        int t = p / 13, j0 = (p % 13) * 4;
        float4 a = {0.f, 0.f, 0.f, 0.f};
        #pragma unroll
        for (int d = 0; d < 80; d++) {
            float qv = qT[d][t];
            float4 kv = *(const float4*)&kT[d][j0];
            a.x += qv * kv.x; a.y += qv * kv.y; a.z += qv * kv.z; a.w += qv * kv.w;
        }
        a.x *= scale; a.y *= scale; a.z *= scale; a.w *= scale;
        *(float4*)&ss[t][j0] = a;
    }
    __syncthreads();
    // parallel softmax: 4 lanes per row (196 threads), shfl_xor reduce within 4-lane group
    if (tid < 196) {
        const int r = tid >> 2, sub = tid & 3;
        const int j0 = sub * 13;
        const int j1 = (sub == 3) ? 10 : 13;
        const int myr = rid[r];
        float mx = -1e30f;
        for (int i = 0; i < j1; i++) {
            float v = ss[r][j0 + i];
            if (shift && rid[j0 + i] != myr) v = -1e9f;
            ss[r][j0 + i] = v;
            mx = fmaxf(mx, v);
        }
        mx = fmaxf(mx, __shfl_xor(mx, 1));
        mx = fmaxf(mx, __shfl_xor(mx, 2));
        float sum = 0.f;
        for (int i = 0; i < j1; i++) {
            float e = __expf(ss[r][j0 + i] - mx);
            ss[r][j0 + i] = e;
            sum += e;
        }
        sum += __shfl_xor(sum, 1);
        sum += __shfl_xor(sum, 2);
        const float inv = 1.f / sum;
        for (int i = 0; i < j1; i++) ss[r][j0 + i] *= inv;
    }
    __syncthreads();
    for (int p = tid; p < 49 * 20; p += 256) {
        int t = p / 20, dv = (p % 20) * 4;
        float4 a = {0.f, 0.f, 0.f, 0.f};
        for (int j = 0; j < 49; j++) {
            float w = ss[t][j];
            float4 vv = *(const float4*)&vs[j][dv];
            a.x += w * vv.x; a.y += w * vv.y; a.z += w * vv.z; a.w += w * vv.w;
        }
        long base = (long)toks[t] * DD + hd * 80 + dv;
        o[base + 0] = __float2bfloat16(a.x);
        o[base + 1] = __float2bfloat16(a.y);
        o[base + 2] = __float2bfloat16(a.z);
        o[base + 3] = __float2bfloat16(a.w);
    }
}

// ---- inverse NSCT: reads bf16 y-mirror (ayc cols [64,640)), writes ayc cols [0,64) ----
__global__ __launch_bounds__(256)
void ict_kernel(__hip_bfloat16* ayc, const float* __restrict__ filt) {
    __shared__ float sf[225];
    for (int i = threadIdx.x; i < 225; i += 256) sf[i] = filt[i];
    __syncthreads();
    int id = blockIdx.x * 256 + threadIdx.x;   // NTOK * 16
    int c4 = (id & 15) << 2;
    int pix = id >> 4;
    int w = pix % 56, h = (pix / 56) % 56, b = pix / 3136;
    float4 a = {0.f, 0.f, 0.f, 0.f};
    #pragma unroll
    for (int dy = 0; dy < 5; dy++) {
        int hy = h + dy - 2;
        if (hy < 0 || hy >= 56) continue;
        #pragma unroll
        for (int dx = 0; dx < 5; dx++) {
            int wx = w + dx - 2;
            if (wx < 0 || wx >= 56) continue;
            const __hip_bfloat16* yr = ayc + ((long)(b * 56 + hy) * 56 + wx) * DD + 64 + c4;
            #pragma unroll
            for (int band = 0; band < 9; band++) {
                const float f = sf[band*25 + dy*5 + dx];
                const short4 sv = *(const short4*)&yr[band * 64];
                a.x += bf2f(sv.x) * f; a.y += bf2f(sv.y) * f;
                a.z += bf2f(sv.z) * f; a.w += bf2f(sv.w) * f;
            }
        }
    }
    short4 p;
    p.x = f2bf(a.x); p.y = f2bf(a.y); p.z = f2bf(a.z); p.w = f2bf(a.w);
    *(short4*)&ayc[(long)pix * DD + c4] = p;
}

// ---------------- host ----------------
extern "C" void kernel_launch(void* const* d_in, const int* in_sizes, int n_in,
                              void* d_out, int out_size, void* d_ws, size_t ws_size,
                              hipStream_t stream) {
    (void)in_sizes; (void)n_in; (void)out_size; (void)ws_size;
    const float* x      = (const float*)d_in[0];
    const float* ln1_g  = (const float*)d_in[1];
    const float* ln1_b  = (const float*)d_in[2];
    const float* qkv_w  = (const float*)d_in[3];
    const float* qkv_b  = (const float*)d_in[4];
    const float* proj_w = (const float*)d_in[5];
    const float* proj_b = (const float*)d_in[6];
    const float* ln2_g  = (const float*)d_in[7];
    const float* ln2_b  = (const float*)d_in[8];
    const float* fc1_w  = (const float*)d_in[9];
    const float* fc1_b  = (const float*)d_in[10];
    const float* fc2_w  = (const float*)d_in[11];
    const float* fc2_b  = (const float*)d_in[12];
    const float* lin_w  = (const float*)d_in[13];
    const float* lin_b  = (const float*)d_in[14];
    const float* conv_w = (const float*)d_in[15];
    const float* conv_b = (const float*)d_in[16];

    char* ws = (char*)d_ws;
    size_t off = 0;
    auto alloc = [&](size_t bytes) -> void* {
        void* p = ws + off;
        off += (bytes + 255) & ~(size_t)255;
        return p;
    };
    float* filt   = (float*)alloc(225 * 4);
    float* linbp  = (float*)alloc(640 * 4);
    float* convbp = (float*)alloc(128 * 4);
    __hip_bfloat16* qkvWt[2], *projWt[2], *fc1Wt[2], *fc2Wt[2];
    for (int i = 0; i < 2; i++) qkvWt[i] = (__hip_bfloat16*)alloc(1920L * 640 * 2);
    for (int i = 0; i < 2; i++) projWt[i] = (__hip_bfloat16*)alloc(640L * 640 * 2);
    for (int i = 0; i < 2; i++) fc1Wt[i] = (__hip_bfloat16*)alloc(2560L * 640 * 2);
    for (int i = 0; i < 2; i++) fc2Wt[i] = (__hip_bfloat16*)alloc(640L * 2560 * 2);
    __hip_bfloat16* linWt  = (__hip_bfloat16*)alloc(640L * 640 * 2);   // N padded 576->640
    __hip_bfloat16* convWt = (__hip_bfloat16*)alloc(128L * 640 * 2);   // N padded 64->128
    __hip_bfloat16* x3   = (__hip_bfloat16*)alloc((long)NTOK * DD * 2);  // bf16 residual stream
    __hip_bfloat16* bufA = (__hip_bfloat16*)alloc((long)NTOK * DD * 2);
    char* bufB = (char*)alloc((long)NTOK * 2560 * 2);
    __hip_bfloat16* qkv = (__hip_bfloat16*)bufB;
    __hip_bfloat16* h2  = (__hip_bfloat16*)bufB;
    __hip_bfloat16* ayc = (__hip_bfloat16*)(bufB + (long)NTOK * DD * 4);

    hipFuncSetAttribute((const void*)gemm128_kernel,
                        hipFuncAttributeMaxDynamicSharedMemorySize, 32768);

    dim3 tb(32, 8);
    init_consts<<<1, 256, 0, stream>>>(filt, linbp, lin_b, convbp, conv_b);
    for (int i = 0; i < 2; i++) {
        wtrans_kernel<<<dim3(60, 20), tb, 0, stream>>>(qkv_w + (long)i*640*1920, qkvWt[i], 640, 1920);
        wtrans_kernel<<<dim3(20, 20), tb, 0, stream>>>(proj_w + (long)i*640*640,  projWt[i], 640, 640);
        wtrans_kernel<<<dim3(80, 20), tb, 0, stream>>>(fc1_w + (long)i*640*2560, fc1Wt[i], 640, 2560);
        wtrans_kernel<<<dim3(20, 80), tb, 0, stream>>>(fc2_w + (long)i*2560*640, fc2Wt[i], 2560, 640);
    }
    wtrans_kernel<<<dim3(20, 20), tb, 0, stream>>>(lin_w, linWt, 640, 576);
    wcast_kernel<<<320, 256, 0, stream>>>(conv_w, convWt, 64 * 640, 128 * 640);

    // prep: writes x3 bf16 + fused LN1(layer0) bf16 into bufA
    prep_kernel<<<6272, 256, 0, stream>>>(x, filt, x3, ln1_g, ln1_b, bufA);

    for (int i = 0; i < 2; i++) {
        int shift = i ? 3 : 0;
        if (i == 1)   // layer 0's LN1 is fused into prep
            ln_kernel<<<6272, 256, 0, stream>>>(x3, ln1_g + i*640, ln1_b + i*640, bufA);
        // qkv: N=1920 exact (15 col-tiles), bf16 out
        gemm128_kernel<<<dim3(15, 196), 256, 32768, stream>>>(bufA, qkvWt[i], qkv_b + i*1920,
            nullptr, nullptr, qkv, 640, 1920, 0, 1920, 0, 1920, 0);
        attn_kernel<<<4096, 256, 0, stream>>>(qkv, bufA, shift);
        // proj: N=640 exact, resid+out = x3 (bf16, in-place elementwise)
        gemm128_kernel<<<dim3(5, 196), 256, 32768, stream>>>(bufA, projWt[i], proj_b + i*640,
            x3, nullptr, x3, 640, 640, 0, 640, 0, 640, 0);
        ln_kernel<<<6272, 256, 0, stream>>>(x3, ln2_g + i*640, ln2_b + i*640, bufA);
        // fc1: N=2560 exact, gelu, bf16 out
        gemm128_kernel<<<dim3(20, 196), 256, 32768, stream>>>(bufA, fc1Wt[i], fc1_b + i*2560,
            nullptr, nullptr, h2, 640, 2560, 0, 2560, 1, 2560, 0);
        // fc2: N=640 exact, K=2560, resid+out = x3 (bf16)
        gemm128_kernel<<<dim3(5, 196), 256, 32768, stream>>>(h2, fc2Wt[i], fc2_b + i*640,
            x3, nullptr, x3, 2560, 640, 0, 640, 0, 640, 0);
    }
    // lin: A = x3 (bf16), bf16 out into ayc cols [64,640)
    gemm128_kernel<<<dim3(5, 196), 256, 32768, stream>>>(x3, linWt, linbp,
        nullptr, nullptr, ayc, 640, 640, 64, 576, 0, 576, 0);
    ict_kernel<<<1568, 256, 0, stream>>>(ayc, filt);   // fills ayc cols [0,64)
    // conv: N=128 (64 valid), direct NCHW store into d_out (fuses unpack)
    gemm128_kernel<<<dim3(1, 196), 256, 32768, stream>>>(ayc, convWt, convbp,
        nullptr, (float*)d_out, nullptr, 640, 0, 0, 64, 0, 64, 1);
}

// Round 19
// 1269.970 us; speedup vs baseline: 4.1378x; 1.0161x over previous
//
#include <hip/hip_runtime.h>
#include <hip/hip_bf16.h>
#include <math.h>

// ---------------- types ----------------
typedef __attribute__((ext_vector_type(4))) float f32x4;
typedef __attribute__((ext_vector_type(8))) short short8;

#define NTOK 25088   // B*H*W = 8*56*56
#define DD   640

__device__ __forceinline__ void gload_lds16(const void* g, void* l) {
    __builtin_amdgcn_global_load_lds((const __attribute__((address_space(1))) void*)g,
                                     (__attribute__((address_space(3))) void*)l,
                                     16, 0, 0);
}

// exact rewrite of tanh-gelu: 0.5t(1+tanh(v)) = t * sigmoid(2v)
__device__ __forceinline__ float gelu_f(float t) {
    float u = 1.5957691216057308f * (t + 0.044715f * t * t * t);
    float e = __builtin_amdgcn_exp2f(u * -1.4426950408889634f);   // exp(-u)
    return t / (1.f + e);
}

__device__ __forceinline__ float bf2f(short u) {
    union { unsigned int i; float f; } cv;
    cv.i = ((unsigned int)(unsigned short)u) << 16;
    return cv.f;
}
__device__ __forceinline__ short f2bf(float f) {
    return (short)__bfloat16_as_short(__float2bfloat16(f));
}

// ---------------- constants init: NSCT filters + padded biases ----------------
__global__ void init_consts(float* __restrict__ filt, float* __restrict__ linbp,
                            const float* __restrict__ lin_b, float* __restrict__ convbp,
                            const float* __restrict__ conv_b) {
    int t = threadIdx.x;
    if (t == 0) {
        float g[25]; float s = 0.f;
        for (int i = 0; i < 5; i++) for (int j = 0; j < 5; j++) {
            float yy = (float)(i - 2), xx = (float)(j - 2);
            float v = expf(-(xx*xx + yy*yy) * 0.25f);
            g[i*5+j] = v; s += v;
        }
        for (int i = 0; i < 25; i++) { g[i] /= s; filt[i] = g[i]; }
        for (int k = 0; k < 8; k++) {
            float th = (float)k * 3.14159265358979323846f / 8.f;
            float ct = cosf(th), st = sinf(th);
            float d[25]; float mean = 0.f;
            for (int i = 0; i < 5; i++) for (int j = 0; j < 5; j++) {
                float yy = (float)(i - 2), xx = (float)(j - 2);
                d[i*5+j] = (ct*xx + st*yy) * g[i*5+j];
                mean += d[i*5+j];
            }
            mean *= (1.f/25.f);
            float ss = 0.f;
            for (int i = 0; i < 25; i++) { d[i] -= mean; ss += d[i]*d[i]; }
            ss = sqrtf(ss);
            for (int i = 0; i < 25; i++) filt[(k+1)*25 + i] = d[i] / ss;
        }
    }
    for (int i = t; i < 640; i += 256) linbp[i]  = (i < 576) ? lin_b[i]  : 0.f;
    for (int i = t; i < 128; i += 256) convbp[i] = (i < 64)  ? conv_b[i] : 0.f;
}

// ======= fused weight prep: ALL transposes+casts in ONE dispatch (replaces 14 launches) ======
// Segments (32x32 transpose tiles, both layers contiguous per type):
//   [0,2400)     qkv  (2 layers x 60nx x 20ny, K=640,  Nsrc=1920)
//   [2400,3200)  proj (2 x 20 x 20,            K=640,  Nsrc=640)
//   [3200,6400)  fc1  (2 x 80 x 20,            K=640,  Nsrc=2560)
//   [6400,9600)  fc2  (2 x 20 x 80,            K=2560, Nsrc=640)
//   [9600,10000) lin  (20 x 20,                K=640,  Nsrc=576; rows padded to 640)
//   [10000,10320) conv cast: convWt[0:128*640] = bf16(conv_w[i<64*640] else 0)
__global__ __launch_bounds__(256)
void wprep_kernel(const float* __restrict__ qkv_w, const float* __restrict__ proj_w,
                  const float* __restrict__ fc1_w, const float* __restrict__ fc2_w,
                  const float* __restrict__ lin_w, const float* __restrict__ conv_w,
                  __hip_bfloat16* __restrict__ qkvWt, __hip_bfloat16* __restrict__ projWt,
                  __hip_bfloat16* __restrict__ fc1Wt, __hip_bfloat16* __restrict__ fc2Wt,
                  __hip_bfloat16* __restrict__ linWt, __hip_bfloat16* __restrict__ convWt) {
    __shared__ float tile[32][33];
    const int bid = blockIdx.x;
    const int tid = threadIdx.x;
    if (bid >= 10000) {
        int i = (bid - 10000) * 256 + tid;   // < 128*640 = 81920 (320 blocks exactly)
        convWt[i] = __float2bfloat16(i < 64 * 640 ? conv_w[i] : 0.f);
        return;
    }
    const float* src; __hip_bfloat16* dst; int K, Nsrc, nx, t;
    if (bid < 2400) {
        t = bid; int l = t / 1200; t -= l * 1200;
        src = qkv_w + (long)l * 640 * 1920; dst = qkvWt + (long)l * 1920 * 640;
        K = 640; Nsrc = 1920; nx = 60;
    } else if (bid < 3200) {
        t = bid - 2400; int l = t / 400; t -= l * 400;
        src = proj_w + (long)l * 640 * 640; dst = projWt + (long)l * 640 * 640;
        K = 640; Nsrc = 640; nx = 20;
    } else if (bid < 6400) {
        t = bid - 3200; int l = t / 1600; t -= l * 1600;
        src = fc1_w + (long)l * 640 * 2560; dst = fc1Wt + (long)l * 2560 * 640;
        K = 640; Nsrc = 2560; nx = 80;
    } else if (bid < 9600) {
        t = bid - 6400; int l = t / 1600; t -= l * 1600;
        src = fc2_w + (long)l * 2560 * 640; dst = fc2Wt + (long)l * 640 * 2560;
        K = 2560; Nsrc = 640; nx = 20;
    } else {
        t = bid - 9600; src = lin_w; dst = linWt;
        K = 640; Nsrc = 576; nx = 20;
    }
    const int n0 = (t % nx) * 32;
    const int k0 = (t / nx) * 32;
    const int tx = tid & 31, ty = tid >> 5;          // 32 x 8
    #pragma unroll
    for (int r = ty; r < 32; r += 8) {
        int k = k0 + r, n = n0 + tx;
        tile[r][tx] = (n < Nsrc) ? src[(long)k * Nsrc + n] : 0.f;
    }
    __syncthreads();
    #pragma unroll
    for (int r = ty; r < 32; r += 8) {
        int n = n0 + r, k = k0 + tx;
        dst[(long)n * K + k] = __float2bfloat16(tile[tx][r]);
    }
}

// ---- prep: relu + 9-band NSCT conv + concat -> x3 bf16 AND fused LN1(layer0) -> bufA bf16 ----
__global__ __launch_bounds__(256)
void prep_kernel(const float* __restrict__ x, const float* __restrict__ filt,
                 __hip_bfloat16* __restrict__ x3, const float* __restrict__ g1,
                 const float* __restrict__ b1, __hip_bfloat16* __restrict__ lnout) {
    __shared__ float sf[225];
    for (int i = threadIdx.x; i < 225; i += 256) sf[i] = filt[i];
    __syncthreads();
    int id = blockIdx.x * 256 + threadIdx.x;   // B*H*W*C
    int c = id & 63;
    int pix = id >> 6;
    int w = pix % 56, h = (pix / 56) % 56, b = pix / 3136;
    const float* xp = x + (long)(b * 64 + c) * 3136;
    float nb[25];
    #pragma unroll
    for (int dy = 0; dy < 5; dy++) {
        int hy = h + dy - 2;
        #pragma unroll
        for (int dx = 0; dx < 5; dx++) {
            int wx = w + dx - 2;
            float v = 0.f;
            if (hy >= 0 && hy < 56 && wx >= 0 && wx < 56) v = fmaxf(xp[hy*56 + wx], 0.f);
            nb[dy*5 + dx] = v;
        }
    }
    float bo[9];
    __hip_bfloat16* orow = x3 + (long)pix * DD;
    float s = 0.f, s2 = 0.f;
    #pragma unroll
    for (int band = 0; band < 9; band++) {
        float a = 0.f;
        #pragma unroll
        for (int t = 0; t < 25; t++) a += nb[t] * sf[band*25 + t];
        bo[band] = a;
        orow[band*64 + c] = __float2bfloat16(a);
        s += a; s2 += a * a;
    }
    const float ctr = nb[12];
    orow[576 + c] = __float2bfloat16(ctr);     // relu(x) center copy
    s += ctr; s2 += ctr * ctr;
    // wave-wide LN (this wave == this pixel's 64 channels x 10 vals)
    #pragma unroll
    for (int o = 32; o > 0; o >>= 1) { s += __shfl_xor(s, o); s2 += __shfl_xor(s2, o); }
    const float mean = s * (1.f/640.f);
    const float var  = s2 * (1.f/640.f) - mean * mean;
    const float inv  = 1.f / sqrtf(var + 1e-5f);
    __hip_bfloat16* ob = lnout + (long)pix * DD;
    #pragma unroll
    for (int band = 0; band < 9; band++) {
        int ci = band*64 + c;
        ob[ci] = __float2bfloat16((bo[band] - mean) * inv * g1[ci] + b1[ci]);
    }
    ob[576 + c] = __float2bfloat16((ctr - mean) * inv * g1[576 + c] + b1[576 + c]);
}

// ---------------- LayerNorm (per-token over 640, bf16 in) -> bf16 ----------------
__global__ __launch_bounds__(256)
void ln_kernel(const __hip_bfloat16* __restrict__ xin, const float* __restrict__ g,
               const float* __restrict__ bt, __hip_bfloat16* __restrict__ out) {
    const int lane = threadIdx.x & 63;
    const long tok = (long)blockIdx.x * 4 + (threadIdx.x >> 6);
    const __hip_bfloat16* xr = xin + tok * DD;
    float v[10]; float s = 0.f, s2 = 0.f;
    #pragma unroll
    for (int i = 0; i < 10; i++) {
        float t = __bfloat162float(xr[lane + (i << 6)]);
        v[i] = t; s += t; s2 += t*t;
    }
    #pragma unroll
    for (int o = 32; o > 0; o >>= 1) { s += __shfl_xor(s, o); s2 += __shfl_xor(s2, o); }
    const float mean = s * (1.f/640.f);
    const float var  = s2 * (1.f/640.f) - mean * mean;
    const float inv  = 1.f / sqrtf(var + 1e-5f);
    __hip_bfloat16* orow = out + tok * DD;
    #pragma unroll
    for (int i = 0; i < 10; i++) {
        int c = lane + (i << 6);
        orow[c] = __float2bfloat16((v[i] - mean) * inv * g[c] + bt[c]);
    }
}

// ===== 128x128 GEMM, BK=32, double-buffer 32KB, 4 blocks/CU, K-loop unrolled x2 =====
// C = A @ Bt^T + bias [+gelu] [+bf16 resid]; bf16 out (mode 0) or fp32 NCHW scatter (mode 1).
// __launch_bounds__(256,3): reg budget 170, no spill (R11 lesson); runtime occupancy 4 blk/CU
// (128-reg granule caps at 4 waves/SIMD). Swizzle: 16B slot ^= (row>>1)&3 on global source
// + LDS read (rule #21, 0 conflicts). One vmcnt(0)+barrier per K-tile; STAGE(t+1) overlaps.
__global__ __launch_bounds__(256, 3)
void gemm128_kernel(const __hip_bfloat16* __restrict__ A,
                    const __hip_bfloat16* __restrict__ Bt,
                    const float* __restrict__ bias,
                    const __hip_bfloat16* __restrict__ resid,
                    float* __restrict__ Cf,
                    __hip_bfloat16* __restrict__ Cb,
                    int K, int ldb, int col_off, int ncb,
                    int act_gelu, int nvalid, int mode) {
    extern __shared__ __align__(16) char smraw[];   // 2 x 16384B: [A 8192 | B 8192]

    const int tid  = threadIdx.x;
    const int lane = tid & 63;
    const int wv   = tid >> 6;
    const int wr   = wv >> 1;          // 0..1  (M half: 64 rows)
    const int wc   = wv & 1;           // 0..1  (N half: 64 cols)

    // ---- bijective XCD-aware block remap (m204) ----
    const int gx   = gridDim.x;
    const int nwg  = gx * gridDim.y;
    const int orig = blockIdx.y * gx + blockIdx.x;
    const int qq = nwg >> 3, rr = nwg & 7;
    const int xcd = orig & 7, lid = orig >> 3;
    const int wg = (xcd < rr ? xcd * (qq + 1) : rr * (qq + 1) + (xcd - rr) * qq) + lid;
    const long m0 = (long)(wg / gx) * 128;
    const long n0 = (long)(wg % gx) * 128;

    const bool wact = ((int)n0 + (wc << 6)) < nvalid;

    f32x4 acc[4][4];
    #pragma unroll
    for (int i = 0; i < 4; i++)
        #pragma unroll
        for (int j = 0; j < 4; j++) acc[i][j] = (f32x4){0.f, 0.f, 0.f, 0.f};

    // staging: per K-tile(32) each matrix tile is 8KB = 2 x (256 thr x 16B)
    const int r0  = tid >> 2;
    const int sl  = tid & 3;
    const int ssl = sl ^ ((r0 >> 1) & 3);
    const __hip_bfloat16* Agb = A  + (m0 + r0) * (long)K + (ssl << 3);
    const __hip_bfloat16* Bgb = Bt + (n0 + r0) * (long)K + (ssl << 3);
    char* dA = smraw + r0 * 64 + sl * 16;            // linear LDS dest
    char* dB = dA + 8192;

    const int frow = lane & 15;
    const int fks  = lane >> 4;                      // 0..3 (k-slot within K=32)
    const int colA = (fks ^ ((frow >> 1) & 3)) << 4; // swizzled 16B slot -> byte offset

    auto STAGE = [&](int boff, int kt) {
        const long ko = (long)kt << 5;
        gload_lds16(Agb + ko,                dA + boff);
        gload_lds16(Agb + 64 * (long)K + ko, dA + boff + 4096);
        gload_lds16(Bgb + ko,                dB + boff);
        gload_lds16(Bgb + 64 * (long)K + ko, dB + boff + 4096);
    };

#define COMPUTE(BUFOFF)                                                                     \
    do {                                                                                    \
        if (wact) {                                                                         \
            const char* pA = smraw + (BUFOFF);                                              \
            const char* pB = pA + 8192;                                                     \
            short8 af[4], bfr[4];                                                           \
            _Pragma("unroll")                                                               \
            for (int mi = 0; mi < 4; ++mi)                                                  \
                af[mi] = *(const short8*)(pA + ((wr << 6) + (mi << 4) + frow) * 64 + colA); \
            _Pragma("unroll")                                                               \
            for (int nj = 0; nj < 4; ++nj)                                                  \
                bfr[nj] = *(const short8*)(pB + ((wc << 6) + (nj << 4) + frow) * 64 + colA);\
            __builtin_amdgcn_s_setprio(1);                                                  \
            _Pragma("unroll")                                                               \
            for (int mi = 0; mi < 4; ++mi)                                                  \
                _Pragma("unroll")                                                           \
                for (int nj = 0; nj < 4; ++nj)  /* SWAPPED: D rows <- N, cols <- M */       \
                    acc[mi][nj] = __builtin_amdgcn_mfma_f32_16x16x32_bf16(                  \
                        bfr[nj], af[mi], acc[mi][nj], 0, 0, 0);                             \
            __builtin_amdgcn_s_setprio(0);                                                  \
        }                                                                                   \
    } while (0)

    const int nt = K >> 5;                           // EVEN at all call sites (20, 80)
    STAGE(0, 0);
    for (int t = 0; t < nt; t += 2) {
        asm volatile("s_waitcnt vmcnt(0)" ::: "memory");   // tile t landed (own loads)
        __builtin_amdgcn_s_barrier();
        __builtin_amdgcn_sched_barrier(0);
        if (t + 1 < nt) STAGE(16384, t + 1);
        COMPUTE(0);
        asm volatile("s_waitcnt vmcnt(0)" ::: "memory");   // tile t+1 landed
        __builtin_amdgcn_s_barrier();
        __builtin_amdgcn_sched_barrier(0);
        if (t + 2 < nt) STAGE(0, t + 2);
        COMPUTE(16384);
    }
#undef COMPUTE

    if (!wact) return;
    // epilogue: lane holds m = frow (fixed), n = base + fks*4 + r  (4 consecutive cols)
    #pragma unroll
    for (int mi = 0; mi < 4; ++mi) {
        const long row = m0 + (wr << 6) + (mi << 4) + frow;
        #pragma unroll
        for (int nj = 0; nj < 4; ++nj) {
            const int n = (int)n0 + (wc << 6) + (nj << 4) + (fks << 2);
            if (n >= ncb) continue;
            f32x4 v = acc[mi][nj];
            if (bias) {
                const f32x4 bv = *(const f32x4*)&bias[n];
                v += bv;
            }
            if (act_gelu) {
                v[0] = gelu_f(v[0]); v[1] = gelu_f(v[1]); v[2] = gelu_f(v[2]); v[3] = gelu_f(v[3]);
            }
            if (mode == 1) {
                // NCHW scatter: out[(b*64 + n+r)*3136 + pos], row = b*3136 + pos
                const int b = (int)(row / 3136), pos = (int)(row % 3136);
                #pragma unroll
                for (int r = 0; r < 4; ++r)
                    Cf[(long)(b * 64 + n + r) * 3136 + pos] = v[r];
                continue;
            }
            const long base = row * (long)ldb + col_off + n;
            if (resid) {
                const short4 rv = *(const short4*)&resid[base];
                v[0] += bf2f(rv.x); v[1] += bf2f(rv.y);
                v[2] += bf2f(rv.z); v[3] += bf2f(rv.w);
            }
            short4 p;
            p.x = f2bf(v[0]); p.y = f2bf(v[1]); p.z = f2bf(v[2]); p.w = f2bf(v[3]);
            *(short4*)&Cb[base] = p;
        }
    }
}

// ---------------- window attention (per window-head, fp32 in LDS) ----------------
__global__ __launch_bounds__(256)
void attn_kernel(const __hip_bfloat16* __restrict__ qkv, __hip_bfloat16* __restrict__ o,
                 int shift) {
    __shared__ __align__(16) float qT[80][52];
    __shared__ __align__(16) float kT[80][52];
    __shared__ __align__(16) float vs[50][80];
    __shared__ __align__(16) float ss[49][52];
    __shared__ int toks[49];
    __shared__ int rid[49];

    const int tid = threadIdx.x;
    const int win = blockIdx.x >> 3;
    const int hd  = blockIdx.x & 7;
    const int b   = win >> 6;
    const int wh  = (win >> 3) & 7;
    const int ww  = win & 7;

    if (tid < 49) {
        int i = tid / 7, j = tid % 7;
        int ph = wh * 7 + i, pw = ww * 7 + j;
        int sh = ph + shift; if (sh >= 56) sh -= 56;
        int sw = pw + shift; if (sw >= 56) sw -= 56;
        toks[tid] = (b * 56 + sh) * 56 + sw;
        int rh = (ph < 49) ? 0 : ((ph < 53) ? 1 : 2);
        int rw = (pw < 49) ? 0 : ((pw < 53) ? 1 : 2);
        rid[tid] = rh * 3 + rw;
    }
    for (int i = tid; i < 80 * 3; i += 256) {
        int d = i / 3, cc = 49 + (i % 3);
        qT[d][cc] = 0.f; kT[d][cc] = 0.f;
    }
    __syncthreads();
    for (int idx = tid; idx < 49 * 80; idx += 256) {
        int t = idx / 80, d = idx % 80;
        long base = (long)toks[t] * 1920 + hd * 80 + d;
        qT[d][t] = __bfloat162float(qkv[base]);
        kT[d][t] = __bfloat162float(qkv[base + 640]);
        vs[t][d] = __bfloat162float(qkv[base + 1280]);
    }
    __syncthreads();
    const float scale = 0.11180339887498948f;
    for (int p = tid; p < 49 * 13; p += 256) {
        int t = p / 13, j0 = (p % 13) * 4;
        float4 a = {0.f, 0.f, 0.f, 0.f};
        #pragma unroll
        for (int d = 0; d < 80; d++) {
            float qv = qT[d][t];
            float4 kv = *(const float4*)&kT[d][j0];
            a.x += qv * kv.x; a.y += qv * kv.y; a.z += qv * kv.z; a.w += qv * kv.w;
        }
        a.x *= scale; a.y *= scale; a.z *= scale; a.w *= scale;
        *(float4*)&ss[t][j0] = a;
    }
    __syncthreads();
    // parallel softmax: 4 lanes per row (196 threads), shfl_xor reduce within 4-lane group
    if (tid < 196) {
        const int r = tid >> 2, sub = tid & 3;
        const int j0 = sub * 13;
        const int j1 = (sub == 3) ? 10 : 13;
        const int myr = rid[r];
        float mx = -1e30f;
        for (int i = 0; i < j1; i++) {
            float v = ss[r][j0 + i];
            if (shift && rid[j0 + i] != myr) v = -1e9f;
            ss[r][j0 + i] = v;
            mx = fmaxf(mx, v);
        }
        mx = fmaxf(mx, __shfl_xor(mx, 1));
        mx = fmaxf(mx, __shfl_xor(mx, 2));
        float sum = 0.f;
        for (int i = 0; i < j1; i++) {
            float e = __expf(ss[r][j0 + i] - mx);
            ss[r][j0 + i] = e;
            sum += e;
        }
        sum += __shfl_xor(sum, 1);
        sum += __shfl_xor(sum, 2);
        const float inv = 1.f / sum;
        for (int i = 0; i < j1; i++) ss[r][j0 + i] *= inv;
    }
    __syncthreads();
    for (int p = tid; p < 49 * 20; p += 256) {
        int t = p / 20, dv = (p % 20) * 4;
        float4 a = {0.f, 0.f, 0.f, 0.f};
        for (int j = 0; j < 49; j++) {
            float w = ss[t][j];
            float4 vv = *(const float4*)&vs[j][dv];
            a.x += w * vv.x; a.y += w * vv.y; a.z += w * vv.z; a.w += w * vv.w;
        }
        long base = (long)toks[t] * DD + hd * 80 + dv;
        o[base + 0] = __float2bfloat16(a.x);
        o[base + 1] = __float2bfloat16(a.y);
        o[base + 2] = __float2bfloat16(a.z);
        o[base + 3] = __float2bfloat16(a.w);
    }
}

// ---- inverse NSCT: reads bf16 y-mirror (ayc cols [64,640)), writes ayc cols [0,64) ----
__global__ __launch_bounds__(256)
void ict_kernel(__hip_bfloat16* ayc, const float* __restrict__ filt) {
    __shared__ float sf[225];
    for (int i = threadIdx.x; i < 225; i += 256) sf[i] = filt[i];
    __syncthreads();
    int id = blockIdx.x * 256 + threadIdx.x;   // NTOK * 16
    int c4 = (id & 15) << 2;
    int pix = id >> 4;
    int w = pix % 56, h = (pix / 56) % 56, b = pix / 3136;
    float4 a = {0.f, 0.f, 0.f, 0.f};
    #pragma unroll
    for (int dy = 0; dy < 5; dy++) {
        int hy = h + dy - 2;
        if (hy < 0 || hy >= 56) continue;
        #pragma unroll
        for (int dx = 0; dx < 5; dx++) {
            int wx = w + dx - 2;
            if (wx < 0 || wx >= 56) continue;
            const __hip_bfloat16* yr = ayc + ((long)(b * 56 + hy) * 56 + wx) * DD + 64 + c4;
            #pragma unroll
            for (int band = 0; band < 9; band++) {
                const float f = sf[band*25 + dy*5 + dx];
                const short4 sv = *(const short4*)&yr[band * 64];
                a.x += bf2f(sv.x) * f; a.y += bf2f(sv.y) * f;
                a.z += bf2f(sv.z) * f; a.w += bf2f(sv.w) * f;
            }
        }
    }
    short4 p;
    p.x = f2bf(a.x); p.y = f2bf(a.y); p.z = f2bf(a.z); p.w = f2bf(a.w);
    *(short4*)&ayc[(long)pix * DD + c4] = p;
}

// ---------------- host ----------------
extern "C" void kernel_launch(void* const* d_in, const int* in_sizes, int n_in,
                              void* d_out, int out_size, void* d_ws, size_t ws_size,
                              hipStream_t stream) {
    (void)in_sizes; (void)n_in; (void)out_size; (void)ws_size;
    const float* x      = (const float*)d_in[0];
    const float* ln1_g  = (const float*)d_in[1];
    const float* ln1_b  = (const float*)d_in[2];
    const float* qkv_w  = (const float*)d_in[3];
    const float* qkv_b  = (const float*)d_in[4];
    const float* proj_w = (const float*)d_in[5];
    const float* proj_b = (const float*)d_in[6];
    const float* ln2_g  = (const float*)d_in[7];
    const float* ln2_b  = (const float*)d_in[8];
    const float* fc1_w  = (const float*)d_in[9];
    const float* fc1_b  = (const float*)d_in[10];
    const float* fc2_w  = (const float*)d_in[11];
    const float* fc2_b  = (const float*)d_in[12];
    const float* lin_w  = (const float*)d_in[13];
    const float* lin_b  = (const float*)d_in[14];
    const float* conv_w = (const float*)d_in[15];
    const float* conv_b = (const float*)d_in[16];

    char* ws = (char*)d_ws;
    size_t off = 0;
    auto alloc = [&](size_t bytes) -> void* {
        void* p = ws + off;
        off += (bytes + 255) & ~(size_t)255;
        return p;
    };
    float* filt   = (float*)alloc(225 * 4);
    float* linbp  = (float*)alloc(640 * 4);
    float* convbp = (float*)alloc(128 * 4);
    // contiguous per type: [layer0 | layer1]
    __hip_bfloat16* qkvWt  = (__hip_bfloat16*)alloc(2L * 1920 * 640 * 2);
    __hip_bfloat16* projWt = (__hip_bfloat16*)alloc(2L * 640 * 640 * 2);
    __hip_bfloat16* fc1Wt  = (__hip_bfloat16*)alloc(2L * 2560 * 640 * 2);
    __hip_bfloat16* fc2Wt  = (__hip_bfloat16*)alloc(2L * 640 * 2560 * 2);
    __hip_bfloat16* linWt  = (__hip_bfloat16*)alloc(640L * 640 * 2);   // rows padded 576->640
    __hip_bfloat16* convWt = (__hip_bfloat16*)alloc(128L * 640 * 2);   // rows padded 64->128
    __hip_bfloat16* x3   = (__hip_bfloat16*)alloc((long)NTOK * DD * 2);  // bf16 residual stream
    __hip_bfloat16* bufA = (__hip_bfloat16*)alloc((long)NTOK * DD * 2);
    char* bufB = (char*)alloc((long)NTOK * 2560 * 2);
    __hip_bfloat16* qkv = (__hip_bfloat16*)bufB;
    __hip_bfloat16* h2  = (__hip_bfloat16*)bufB;
    __hip_bfloat16* ayc = (__hip_bfloat16*)(bufB + (long)NTOK * DD * 4);

    hipFuncSetAttribute((const void*)gemm128_kernel,
                        hipFuncAttributeMaxDynamicSharedMemorySize, 32768);

    init_consts<<<1, 256, 0, stream>>>(filt, linbp, lin_b, convbp, conv_b);
    // ONE fused weight-prep dispatch (replaces 13 wtrans + 1 wcast launches)
    wprep_kernel<<<10320, 256, 0, stream>>>(qkv_w, proj_w, fc1_w, fc2_w, lin_w, conv_w,
                                            qkvWt, projWt, fc1Wt, fc2Wt, linWt, convWt);

    // prep: writes x3 bf16 + fused LN1(layer0) bf16 into bufA
    prep_kernel<<<6272, 256, 0, stream>>>(x, filt, x3, ln1_g, ln1_b, bufA);

    for (int i = 0; i < 2; i++) {
        int shift = i ? 3 : 0;
        if (i == 1)   // layer 0's LN1 is fused into prep
            ln_kernel<<<6272, 256, 0, stream>>>(x3, ln1_g + i*640, ln1_b + i*640, bufA);
        // qkv: N=1920 exact (15 col-tiles), bf16 out
        gemm128_kernel<<<dim3(15, 196), 256, 32768, stream>>>(bufA, qkvWt + (long)i*1920*640,
            qkv_b + i*1920, nullptr, nullptr, qkv, 640, 1920, 0, 1920, 0, 1920, 0);
        attn_kernel<<<4096, 256, 0, stream>>>(qkv, bufA, shift);
        // proj: N=640 exact, resid+out = x3 (bf16, in-place elementwise)
        gemm128_kernel<<<dim3(5, 196), 256, 32768, stream>>>(bufA, projWt + (long)i*640*640,
            proj_b + i*640, x3, nullptr, x3, 640, 640, 0, 640, 0, 640, 0);
        ln_kernel<<<6272, 256, 0, stream>>>(x3, ln2_g + i*640, ln2_b + i*640, bufA);
        // fc1: N=2560 exact, gelu, bf16 out
        gemm128_kernel<<<dim3(20, 196), 256, 32768, stream>>>(bufA, fc1Wt + (long)i*2560*640,
            fc1_b + i*2560, nullptr, nullptr, h2, 640, 2560, 0, 2560, 1, 2560, 0);
        // fc2: N=640 exact, K=2560, resid+out = x3 (bf16)
        gemm128_kernel<<<dim3(5, 196), 256, 32768, stream>>>(h2, fc2Wt + (long)i*640*2560,
            fc2_b + i*640, x3, nullptr, x3, 2560, 640, 0, 640, 0, 640, 0);
    }
    // lin: A = x3 (bf16), bf16 out into ayc cols [64,640)
    gemm128_kernel<<<dim3(5, 196), 256, 32768, stream>>>(x3, linWt, linbp,
        nullptr, nullptr, ayc, 640, 640, 64, 576, 0, 576, 0);
    ict_kernel<<<1568, 256, 0, stream>>>(ayc, filt);   // fills ayc cols [0,64)
    // conv: N=128 (64 valid), direct NCHW store into d_out (fuses unpack)
    gemm128_kernel<<<dim3(1, 196), 256, 32768, stream>>>(ayc, convWt, convbp,
        nullptr, (float*)d_out, nullptr, 640, 0, 0, 64, 0, 64, 1);
}